// Round 4
// baseline (334.839 us; speedup 1.0000x reference)
//
#include <hip/hip_runtime.h>
#include <cstdint>

typedef __bf16 bf16x8 __attribute__((ext_vector_type(8)));
typedef unsigned short u16x8 __attribute__((ext_vector_type(8)));
typedef float f32x4 __attribute__((ext_vector_type(4)));

// B=16, S=1024, D=512, T=3, BT=48
// Xb [bt][s][d] bf16 ; Gb [bt][s][d'] bf16 (= X * (SC*Wq^T*Wk)) ; Vt [bt][e][s] bf16
// S/P buffer: [bt_local][q][k] fp16 scores -> bf16 P in place

__device__ __forceinline__ unsigned short f2bf(float x){
  unsigned u = __float_as_uint(x);
  u += 0x7fffu + ((u >> 16) & 1u);
  return (unsigned short)(u >> 16);
}

__device__ __forceinline__ void gload16(const void* src, void* dst){
  auto g = reinterpret_cast<const uint32_t __attribute__((address_space(1)))*>(
             reinterpret_cast<uintptr_t>(src));
  auto l = reinterpret_cast<uint32_t __attribute__((address_space(3)))*>(
             reinterpret_cast<uintptr_t>(dst));
  __builtin_amdgcn_global_load_lds(g, l, 16, 0, 0);
}

#define SCHED0 __builtin_amdgcn_sched_barrier(0)
#define SBAR() do { SCHED0; __builtin_amdgcn_s_barrier(); SCHED0; } while (0)
#define WAITVM(N) do { asm volatile("s_waitcnt vmcnt(" #N ")" ::: "memory"); SCHED0; } while (0)
#define WAITLGKM0() do { asm volatile("s_waitcnt lgkmcnt(0)" ::: "memory"); SCHED0; } while (0)

// ---- 256-thread tile stager (old 128x64 kernels): linear LDS, inv-swizzled source ----
__device__ __forceinline__ void stage_tile(const unsigned short* __restrict__ g, size_t ld,
                                           unsigned short* l, int tid){
  #pragma unroll
  for (int i = 0; i < 4; ++i){
    int j = i * 256 + tid;
    int r = j >> 3, cc = j & 7;
    int c = cc ^ (r & 7);
    gload16(g + (size_t)r * ld + c * 8, l + (size_t)(i * 256 + (tid & 192)) * 8);
  }
}

// ---- 512-thread half-tile stager (128 rows x 64 cols bf16 = 16 KB) ----
__device__ __forceinline__ void stage_half(const unsigned short* __restrict__ g, int ld,
                                           unsigned short* l, int tid){
  #pragma unroll
  for (int i = 0; i < 2; ++i){
    int j = i * 512 + tid;
    int r = j >> 3, cc = j & 7;
    int c = cc ^ (r & 7);
    gload16(g + (size_t)r * ld + c * 8, l + (size_t)(i * 512 + (tid & 448)) * 8);
  }
}

__device__ __forceinline__ bf16x8 frag_at(const unsigned short* l, int row, int kch){
  int ch = kch ^ (row & 7);
  return *(const bf16x8*)(l + (row << 6) + (ch << 3));
}

// ---------- w1 = SC * Wk^T * bq ----------
__global__ void k_w1(const float* __restrict__ Wk, const float* __restrict__ bq,
                     float* __restrict__ w1){
  __shared__ float red[4][64];
  int d = blockIdx.x * 64 + (threadIdx.x & 63);
  int eq = threadIdx.x >> 6;
  float s = 0.f;
  #pragma unroll 8
  for (int e = eq * 128; e < eq * 128 + 128; ++e) s += Wk[(size_t)e * 512 + d] * bq[e];
  red[eq][threadIdx.x & 63] = s;
  __syncthreads();
  if (eq == 0)
    w1[d] = (red[0][threadIdx.x] + red[1][threadIdx.x] + red[2][threadIdx.x] +
             red[3][threadIdx.x]) * 0.04419417382415922f;
}

// ---------- transpose+convert Wq,Wk -> WqT,WkT ([d][e] bf16) ----------
__global__ void k_conv_wt(const float* __restrict__ Wq, const float* __restrict__ Wk,
                          unsigned short* __restrict__ WqT, unsigned short* __restrict__ WkT){
  __shared__ float tl[64][65];
  int bi = blockIdx.x;
  const float* src = (bi & 64) ? Wk : Wq;
  unsigned short* dst = (bi & 64) ? WkT : WqT;
  int te = (bi >> 3) & 7, td = bi & 7;
  int tid = threadIdx.x;
  #pragma unroll
  for (int i = 0; i < 4; ++i){
    int q = i * 256 + tid;
    int r = q >> 4, c4 = q & 15;
    f32x4 v = *(const f32x4*)(src + (size_t)(te * 64 + r) * 512 + td * 64 + c4 * 4);
    tl[r][c4 * 4 + 0] = v[0]; tl[r][c4 * 4 + 1] = v[1];
    tl[r][c4 * 4 + 2] = v[2]; tl[r][c4 * 4 + 3] = v[3];
  }
  __syncthreads();
  #pragma unroll
  for (int i = 0; i < 2; ++i){
    int q = i * 256 + tid;
    int r = q >> 3, c8 = q & 7;
    u16x8 o;
    #pragma unroll
    for (int j = 0; j < 8; ++j) o[j] = f2bf(tl[c8 * 8 + j][r]);
    *(u16x8*)(dst + (size_t)(td * 64 + r) * 512 + te * 64 + c8 * 8) = o;
  }
}

// ---------- convert Wv fp32 -> bf16 ----------
__global__ void k_conv_wv(const float* __restrict__ Wv, unsigned short* __restrict__ out){
  size_t e = ((size_t)blockIdx.x * 256 + threadIdx.x) * 8;
  f32x4 v0 = *(const f32x4*)(Wv + e), v1 = *(const f32x4*)(Wv + e + 4);
  u16x8 o;
  o[0] = f2bf(v0[0]); o[1] = f2bf(v0[1]); o[2] = f2bf(v0[2]); o[3] = f2bf(v0[3]);
  o[4] = f2bf(v1[0]); o[5] = f2bf(v1[1]); o[6] = f2bf(v1[2]); o[7] = f2bf(v1[3]);
  *(u16x8*)(out + e) = o;
}

// ---------- features fp32 -> bf16 stacked + column bias v = X*w1 ----------
__global__ void k_conv_feat(const float* __restrict__ f0, const float* __restrict__ f1,
                            const float* __restrict__ f2, const float* __restrict__ w1,
                            unsigned short* __restrict__ Xb, float* __restrict__ vcol){
  size_t i = (size_t)blockIdx.x * blockDim.x + threadIdx.x;
  size_t e = i * 8;
  size_t bt = e >> 19;
  size_t rest = e & ((1u << 19) - 1);
  int b = (int)(bt / 3), t = (int)(bt % 3);
  const float* src = (t == 0 ? f0 : (t == 1 ? f1 : f2)) + ((size_t)b << 19) + rest;
  f32x4 v0 = *(const f32x4*)(src);
  f32x4 v1 = *(const f32x4*)(src + 4);
  u16x8 o;
  o[0] = f2bf(v0[0]); o[1] = f2bf(v0[1]); o[2] = f2bf(v0[2]); o[3] = f2bf(v0[3]);
  o[4] = f2bf(v1[0]); o[5] = f2bf(v1[1]); o[6] = f2bf(v1[2]); o[7] = f2bf(v1[3]);
  *(u16x8*)(Xb + e) = o;
  int l = threadIdx.x & 63;
  f32x4 wa = *(const f32x4*)(w1 + l * 8);
  f32x4 wb = *(const f32x4*)(w1 + l * 8 + 4);
  float p = v0[0]*wa[0] + v0[1]*wa[1] + v0[2]*wa[2] + v0[3]*wa[3]
          + v1[0]*wb[0] + v1[1]*wb[1] + v1[2]*wb[2] + v1[3]*wb[3];
  p += __shfl_xor(p, 1);  p += __shfl_xor(p, 2);  p += __shfl_xor(p, 4);
  p += __shfl_xor(p, 8);  p += __shfl_xor(p, 16); p += __shfl_xor(p, 32);
  if (l == 0) vcol[i >> 6] = p;
}

// ---------- Mt = SC * WkT * WqT^T  (512x512, 128^2 tiles, 256 threads) ----------
__global__ __launch_bounds__(256, 2)
void k_gemm_mt(const unsigned short* __restrict__ A, const unsigned short* __restrict__ Bm,
               unsigned short* __restrict__ C, float scale){
  __shared__ __align__(16) unsigned short Al[2][8192];
  __shared__ __align__(16) unsigned short Bl[2][8192];
  const int tid = threadIdx.x;
  const int l  = tid & 63;
  const int wid = tid >> 6;
  const int lr = l & 15;
  const int lg = l >> 4;
  const int rb = blockIdx.x >> 2, cb = blockIdx.x & 3;
  const unsigned short* Ab = A + (size_t)rb * 128 * 512;
  const unsigned short* Bb = Bm + (size_t)cb * 128 * 512;

  const f32x4 zero4 = {0.f, 0.f, 0.f, 0.f};
  f32x4 acc[4][4];
  #pragma unroll
  for (int i = 0; i < 4; ++i)
    #pragma unroll
    for (int j = 0; j < 4; ++j) acc[i][j] = zero4;

  stage_tile(Ab, 512, &Al[0][0], tid);
  stage_tile(Bb, 512, &Bl[0][0], tid);
  __syncthreads();

  const int wr = wid >> 1, wc = wid & 1;

  for (int kb = 0; kb < 8; ++kb){
    const int cur = kb & 1;
    if (kb < 7){
      stage_tile(Ab + (kb + 1) * 64, 512, &Al[cur ^ 1][0], tid);
      stage_tile(Bb + (kb + 1) * 64, 512, &Bl[cur ^ 1][0], tid);
    }
    #pragma unroll
    for (int ks = 0; ks < 2; ++ks){
      bf16x8 af[4], bf[4];
      #pragma unroll
      for (int i = 0; i < 4; ++i) af[i] = frag_at(&Al[cur][0], wr * 64 + i * 16 + lr, ks * 4 + lg);
      #pragma unroll
      for (int j = 0; j < 4; ++j) bf[j] = frag_at(&Bl[cur][0], wc * 64 + j * 16 + lr, ks * 4 + lg);
      #pragma unroll
      for (int i = 0; i < 4; ++i)
        #pragma unroll
        for (int j = 0; j < 4; ++j)
          acc[i][j] = __builtin_amdgcn_mfma_f32_16x16x32_bf16(af[i], bf[j], acc[i][j], 0, 0, 0);
    }
    __syncthreads();
  }

  #pragma unroll
  for (int j = 0; j < 4; ++j){
    int col = cb * 128 + wc * 64 + j * 16 + lr;
    #pragma unroll
    for (int i = 0; i < 4; ++i){
      int row0 = rb * 128 + wr * 64 + i * 16 + lg * 4;
      #pragma unroll
      for (int r = 0; r < 4; ++r)
        C[(size_t)(row0 + r) * 512 + col] = f2bf(acc[i][j][r] * scale);
    }
  }
}

// ---------- 256x256 8-phase GEMM (T2+T3+T4+T5). MODE: 0 GPROJ, 1 VTPROJ, 2 QK, 3 PV ----------
// All compute C = A * B^T over K, bf16 in, fp32 acc.
//  0: A=Xb(49152x512), B=Mt(512x512)       -> Gb bf16 [row*512+col]
//  1: A=Wv16(512x512), B=Xb(49152x512), +bv[row] -> Vt bf16 [(col>>10)<<19 | row<<10 | col&1023]
//  2: A=Gb, B=Xb per bt (1024x1024x512)    -> S fp16 [btl<<20 | row<<10 | col]
//  3: A=P (per local b, 1024x3072), B=Vt   -> atomicAdd f32 out[b<<19 | row<<9 | col], split-K=2
template<int MODE>
__global__ __launch_bounds__(512, 2)
void k_mm8(const unsigned short* __restrict__ A, const unsigned short* __restrict__ Bm,
           const float* __restrict__ bias, void* __restrict__ Cv, int bt0){
  __shared__ __align__(16) unsigned short Asl[2][16384];
  __shared__ __align__(16) unsigned short Bsl[2][16384];
  const int tid = threadIdx.x;
  const int l = tid & 63, wid = tid >> 6;
  const int lr = l & 15, lg = l >> 4;
  const int wr = wid >> 2, wc = wid & 3;      // wave grid 2(M) x 4(N)
  const int cpx = gridDim.x >> 3;
  const int wg = (blockIdx.x & 7) * cpx + (blockIdx.x >> 3);

  int rb, cb, bidx = 0, kh = 0;
  if (MODE == 0){ rb = wg >> 1; cb = wg & 1; }
  else if (MODE == 1){ rb = wg & 1; cb = wg >> 1; }
  else if (MODE == 2){ bidx = wg >> 4; int tl = wg & 15; rb = tl >> 2; cb = tl & 3; }
  else { bidx = wg >> 4; int sub = wg & 15; kh = sub >> 3; int tl = sub & 7; rb = tl >> 1; cb = tl & 1; }

  const int NT  = (MODE == 3) ? 24 : 8;
  const int ldA = (MODE == 3) ? 1024 : 512;
  const int ldB = (MODE == 3) ? 1024 : 512;

  auto aTile = [&](int t) -> const unsigned short* {
    if (MODE == 0 || MODE == 1) return A + (size_t)rb * 256 * 512 + t * 64;
    if (MODE == 2) return A + ((size_t)(bt0 + bidx) << 19) + (size_t)rb * 256 * 512 + t * 64;
    int g = kh * 24 + t; int tt = g >> 4, kk = g & 15;
    return A + ((size_t)(bidx * 3 + tt) << 20) + (size_t)rb * 256 * 1024 + kk * 64;
  };
  auto bTile = [&](int t) -> const unsigned short* {
    if (MODE == 0 || MODE == 1) return Bm + (size_t)cb * 256 * 512 + t * 64;
    if (MODE == 2) return Bm + ((size_t)(bt0 + bidx) << 19) + (size_t)cb * 256 * 512 + t * 64;
    int g = kh * 24 + t; int tt = g >> 4, kk = g & 15;
    return Bm + ((size_t)((bt0 + bidx) * 3 + tt) << 19) + (size_t)cb * 256 * 1024 + kk * 64;
  };

  const f32x4 zero4 = {0.f, 0.f, 0.f, 0.f};
  f32x4 acc[4][2][4];
  #pragma unroll
  for (int s = 0; s < 4; ++s)
    #pragma unroll
    for (int p = 0; p < 2; ++p)
      #pragma unroll
      for (int j = 0; j < 4; ++j) acc[s][p][j] = zero4;

  // ---- prologue: T0 {B0,B1,A0,A1}, T1 {B0,B1,A0} ----
  stage_half(bTile(0),            ldB, &Bsl[0][0],    tid);
  stage_half(bTile(0) + 128*ldB,  ldB, &Bsl[0][8192], tid);
  stage_half(aTile(0),            ldA, &Asl[0][0],    tid);
  stage_half(aTile(0) + 128*ldA,  ldA, &Asl[0][8192], tid);
  stage_half(bTile(1),            ldB, &Bsl[1][0],    tid);
  stage_half(bTile(1) + 128*ldB,  ldB, &Bsl[1][8192], tid);
  stage_half(aTile(1),            ldA, &Asl[1][0],    tid);
  WAITVM(6);
  SBAR();

  // ---- K-loop: 4 phases per K-tile; stripe-interleaved M quadrants ----
  // phase s reads A rows 64s..64s+63 (wave wr takes rows 64s+32wr..+31) and all B (regs).
  // stage schedule: (t,0)->T(t+1).A1 ; (t,1)->T(t+2).B0 ; (t,2)->T(t+2).B1 ; (t,3)->T(t+2).A0.
  // vmcnt(6) once per K-tile at (t,3) confirms T(t+1) fully landed.
  #pragma unroll 1
  for (int t = 0; t < NT; ++t){
    const int st = t & 1;
    unsigned short* Acur = &Asl[st][0];
    unsigned short* Bcur = &Bsl[st][0];
    bf16x8 bfr[4][2];
    #pragma unroll
    for (int s = 0; s < 4; ++s){
      if (s == 0){
        #pragma unroll
        for (int j = 0; j < 4; ++j)
          #pragma unroll
          for (int kk = 0; kk < 2; ++kk)
            bfr[j][kk] = frag_at(Bcur, wc * 64 + j * 16 + lr, kk * 4 + lg);
      }
      bf16x8 afr[2][2];
      #pragma unroll
      for (int p = 0; p < 2; ++p)
        #pragma unroll
        for (int kk = 0; kk < 2; ++kk)
          afr[p][kk] = frag_at(Acur, 64 * s + 32 * wr + p * 16 + lr, kk * 4 + lg);

      if (s == 0){
        if (t + 1 < NT) stage_half(aTile(t + 1) + 128*ldA, ldA, &Asl[(t + 1) & 1][8192], tid);
      } else if (s == 1){
        if (t + 2 < NT) stage_half(bTile(t + 2),           ldB, &Bsl[st][0],    tid);
      } else if (s == 2){
        if (t + 2 < NT) stage_half(bTile(t + 2) + 128*ldB, ldB, &Bsl[st][8192], tid);
      } else {
        if (t + 2 < NT) stage_half(aTile(t + 2),           ldA, &Asl[st][0],    tid);
        if (t < NT - 2) { WAITVM(6); } else if (t == NT - 2) { WAITVM(0); }
      }

      SBAR();
      WAITLGKM0();
      __builtin_amdgcn_s_setprio(1);
      #pragma unroll
      for (int p = 0; p < 2; ++p)
        #pragma unroll
        for (int j = 0; j < 4; ++j)
          #pragma unroll
          for (int kk = 0; kk < 2; ++kk)
            acc[s][p][j] = __builtin_amdgcn_mfma_f32_16x16x32_bf16(afr[p][kk], bfr[j][kk], acc[s][p][j], 0, 0, 0);
      __builtin_amdgcn_s_setprio(0);
      SBAR();
    }
  }

  // ---- epilogue ----
  const int row0 = rb * 256 + 32 * wr + lg * 4;
  const int col0 = cb * 256 + wc * 64 + lr;
  #pragma unroll
  for (int s = 0; s < 4; ++s)
    #pragma unroll
    for (int p = 0; p < 2; ++p)
      #pragma unroll
      for (int j = 0; j < 4; ++j){
        const int col = col0 + j * 16;
        #pragma unroll
        for (int r = 0; r < 4; ++r){
          const int row = row0 + 64 * s + 16 * p + r;
          float v = acc[s][p][j][r];
          if (MODE == 0){
            ((unsigned short*)Cv)[(size_t)row * 512 + col] = f2bf(v);
          } else if (MODE == 1){
            v += bias[row];
            ((unsigned short*)Cv)[((size_t)(col >> 10) << 19) + ((size_t)row << 10) + (col & 1023)] = f2bf(v);
          } else if (MODE == 2){
            _Float16 h = (_Float16)v;
            ((unsigned short*)Cv)[((size_t)bidx << 20) + ((size_t)row << 10) + col] =
                __builtin_bit_cast(unsigned short, h);
          } else {
            atomicAdd((float*)Cv + (((size_t)(bt0 + bidx)) << 19) + ((size_t)row << 9) + col, v);
          }
        }
      }
}

// ---------- softmax rows in place: fp16 S (+v col bias) -> bf16 P = w[t]*exp/l ----------
__global__ __launch_bounds__(256)
void k_softmax(unsigned short* __restrict__ S, const float* __restrict__ vcol,
               const float* __restrict__ tfw, int bt0){
  const int wid = threadIdx.x >> 6, l = threadIdx.x & 63;
  const size_t row = (size_t)blockIdx.x * 4 + wid;
  const int bt = bt0 + (int)(row >> 10);
  const int t = bt % 3;
  float t0 = tfw[0], t1 = tfw[1], t2 = tfw[2];
  float tm = fmaxf(t0, fmaxf(t1, t2));
  float e0 = __expf(t0 - tm), e1 = __expf(t1 - tm), e2 = __expf(t2 - tm);
  float w = (t == 0 ? e0 : (t == 1 ? e1 : e2)) / (e0 + e1 + e2);

  const float* vr = vcol + ((size_t)bt << 10) + l * 16;
  unsigned short* rp = S + (row << 10) + l * 16;
  u16x8 a = *(const u16x8*)rp;
  u16x8 b = *(const u16x8*)(rp + 8);
  f32x4 va0 = *(const f32x4*)(vr), va1 = *(const f32x4*)(vr + 4);
  f32x4 va2 = *(const f32x4*)(vr + 8), va3 = *(const f32x4*)(vr + 12);
  float x[16];
  #pragma unroll
  for (int j = 0; j < 8; ++j){
    x[j]     = (float)__builtin_bit_cast(_Float16, (unsigned short)a[j]);
    x[8 + j] = (float)__builtin_bit_cast(_Float16, (unsigned short)b[j]);
  }
  x[0] += va0[0]; x[1] += va0[1]; x[2]  += va0[2]; x[3]  += va0[3];
  x[4] += va1[0]; x[5] += va1[1]; x[6]  += va1[2]; x[7]  += va1[3];
  x[8] += va2[0]; x[9] += va2[1]; x[10] += va2[2]; x[11] += va2[3];
  x[12]+= va3[0]; x[13]+= va3[1]; x[14] += va3[2]; x[15] += va3[3];
  float m = x[0];
  #pragma unroll
  for (int j = 1; j < 16; ++j) m = fmaxf(m, x[j]);
  m = fmaxf(m, __shfl_xor(m, 1));
  m = fmaxf(m, __shfl_xor(m, 2));
  m = fmaxf(m, __shfl_xor(m, 4));
  m = fmaxf(m, __shfl_xor(m, 8));
  m = fmaxf(m, __shfl_xor(m, 16));
  m = fmaxf(m, __shfl_xor(m, 32));
  float s = 0.f;
  #pragma unroll
  for (int j = 0; j < 16; ++j){ x[j] = __expf(x[j] - m); s += x[j]; }
  s += __shfl_xor(s, 1);
  s += __shfl_xor(s, 2);
  s += __shfl_xor(s, 4);
  s += __shfl_xor(s, 8);
  s += __shfl_xor(s, 16);
  s += __shfl_xor(s, 32);
  float sc = w / s;
  u16x8 oa, ob;
  #pragma unroll
  for (int j = 0; j < 8; ++j){
    oa[j] = f2bf(x[j] * sc);
    ob[j] = f2bf(x[8 + j] * sc);
  }
  *(u16x8*)rp = oa;
  *(u16x8*)(rp + 8) = ob;
}

extern "C" void kernel_launch(void* const* d_in, const int* in_sizes, int n_in,
                              void* d_out, int out_size, void* d_ws, size_t ws_size,
                              hipStream_t stream){
  (void)in_sizes; (void)n_in; (void)out_size;
  const float* f4h = (const float*)d_in[0];
  const float* f1d = (const float*)d_in[1];
  const float* f1w = (const float*)d_in[2];
  const float* Wq  = (const float*)d_in[3];
  const float* bq  = (const float*)d_in[4];
  const float* Wk  = (const float*)d_in[5];
  const float* bk  = (const float*)d_in[6];
  const float* Wv  = (const float*)d_in[7];
  const float* bv  = (const float*)d_in[8];
  const float* tfw = (const float*)d_in[9];
  (void)bk;  // row-constant in scores: cancels in softmax
  float* out = (float*)d_out;

  const size_t N48 = (size_t)48 * 1024 * 512;     // 25165824 elems
  unsigned short* Gb  = (unsigned short*)d_ws;
  unsigned short* Xb  = Gb + N48;
  unsigned short* Vt  = Xb + N48;
  float*          vcol = (float*)(Vt + N48);      // 49152 f32
  unsigned short* WqT = (unsigned short*)(vcol + 49152);
  unsigned short* WkT = WqT + 262144;
  unsigned short* Wv16= WkT + 262144;
  unsigned short* Mt  = Wv16 + 262144;
  float*          w1  = (float*)(Mt + 262144);    // 512 f32
  unsigned short* Sb  = WqT;                      // S/P overlays weights region

  const float SC = 0.04419417382415922f;          // 1/sqrt(512)
  const size_t base = 3 * N48 * 2 + 49152 * 4;    // bytes before Sb
  const size_t s_full = (size_t)48 * 1024 * 1024 * 2;

  k_w1<<<8, 256, 0, stream>>>(Wk, bq, w1);
  k_conv_wt<<<128, 256, 0, stream>>>(Wq, Wk, WqT, WkT);
  k_conv_wv<<<128, 256, 0, stream>>>(Wv, Wv16);
  k_conv_feat<<<12288, 256, 0, stream>>>(f4h, f1d, f1w, w1, Xb, vcol);
  k_gemm_mt<<<16, 256, 0, stream>>>(WkT, WqT, Mt, SC);
  k_mm8<0><<<384, 512, 0, stream>>>(Xb, Mt, nullptr, Gb, 0);       // Gb = Xb * Mt^T
  k_mm8<1><<<384, 512, 0, stream>>>(Wv16, Xb, bv, Vt, 0);          // Vt = (Wv Xb^T + bv)
  hipMemsetAsync(out, 0, (size_t)16 * 1024 * 512 * 4, stream);     // PV accumulates atomically

  if (ws_size >= base + 2048 + s_full){
    k_mm8<2><<<768, 512, 0, stream>>>(Gb, Xb, nullptr, Sb, 0);     // S = Gb * Xb^T
    k_softmax<<<12288, 256, 0, stream>>>(Sb, vcol, tfw, 0);
    k_mm8<3><<<256, 512, 0, stream>>>(Sb, Vt, nullptr, out, 0);    // out += P * V (split-K=2)
  } else {
    for (int h = 0; h < 2; ++h){
      int bt0 = h * 24;
      k_mm8<2><<<384, 512, 0, stream>>>(Gb, Xb, nullptr, Sb, bt0);
      k_softmax<<<6144, 256, 0, stream>>>(Sb, vcol, tfw, bt0);
      k_mm8<3><<<128, 512, 0, stream>>>(Sb, Vt, nullptr, out, h * 8);
    }
  }
}

// Round 5
// 268.742 us; speedup vs baseline: 1.2459x; 1.2459x over previous
//
#include <hip/hip_runtime.h>
#include <cstdint>

typedef __bf16 bf16x8 __attribute__((ext_vector_type(8)));
typedef unsigned short u16x8 __attribute__((ext_vector_type(8)));
typedef float f32x4 __attribute__((ext_vector_type(4)));

// B=16, S=1024, D=512, T=3, BT=48
// Xb [bt][s][d] bf16 ; Gb [bt][s][d'] bf16 (= X * (SC*Wq^T*Wk)) ; Vt [bt][e][s] bf16
// S/P buffer: [bt_local][q][k] fp16 scores -> bf16 P in place

__device__ __forceinline__ unsigned short f2bf(float x){
  unsigned u = __float_as_uint(x);
  u += 0x7fffu + ((u >> 16) & 1u);
  return (unsigned short)(u >> 16);
}

__device__ __forceinline__ void gload16(const void* src, void* dst){
  auto g = reinterpret_cast<const uint32_t __attribute__((address_space(1)))*>(
             reinterpret_cast<uintptr_t>(src));
  auto l = reinterpret_cast<uint32_t __attribute__((address_space(3)))*>(
             reinterpret_cast<uintptr_t>(dst));
  __builtin_amdgcn_global_load_lds(g, l, 16, 0, 0);
}

// stage one 128x64 bf16 tile: linear LDS chunks, inverse-swizzled global source.
// LDS chunk (r,cc) receives global chunk c = cc ^ (r&7); readers use the same XOR.
__device__ __forceinline__ void stage_tile(const unsigned short* __restrict__ g, size_t ld,
                                           unsigned short* l, int tid){
  #pragma unroll
  for (int i = 0; i < 4; ++i){
    int j = i * 256 + tid;
    int r = j >> 3, cc = j & 7;
    int c = cc ^ (r & 7);
    gload16(g + (size_t)r * ld + c * 8, l + (size_t)(i * 256 + (tid & 192)) * 8);
  }
}

__device__ __forceinline__ bf16x8 frag_at(const unsigned short* l, int row, int kch){
  int ch = kch ^ (row & 7);
  return *(const bf16x8*)(l + (row << 6) + (ch << 3));
}

// ---------- merged prologue: conv_wt (blocks 0-127), conv_wv (128-255), w1 (256-263) ----------
__global__ void k_prep(const float* __restrict__ Wq, const float* __restrict__ Wk,
                       const float* __restrict__ Wv, const float* __restrict__ bq,
                       unsigned short* __restrict__ WqT, unsigned short* __restrict__ WkT,
                       unsigned short* __restrict__ Wv16, float* __restrict__ w1){
  __shared__ float sh[64 * 65];
  const int bi = blockIdx.x;
  const int tid = threadIdx.x;
  if (bi < 128){
    // transpose+convert Wq,Wk -> WqT,WkT ([d][e] bf16)
    const float* src = (bi & 64) ? Wk : Wq;
    unsigned short* dst = (bi & 64) ? WkT : WqT;
    int te = (bi >> 3) & 7, td = bi & 7;
    #pragma unroll
    for (int i = 0; i < 4; ++i){
      int q = i * 256 + tid;
      int r = q >> 4, c4 = q & 15;
      f32x4 v = *(const f32x4*)(src + (size_t)(te * 64 + r) * 512 + td * 64 + c4 * 4);
      sh[r * 65 + c4 * 4 + 0] = v[0]; sh[r * 65 + c4 * 4 + 1] = v[1];
      sh[r * 65 + c4 * 4 + 2] = v[2]; sh[r * 65 + c4 * 4 + 3] = v[3];
    }
    __syncthreads();
    #pragma unroll
    for (int i = 0; i < 2; ++i){
      int q = i * 256 + tid;
      int r = q >> 3, c8 = q & 7;
      u16x8 o;
      #pragma unroll
      for (int j = 0; j < 8; ++j) o[j] = f2bf(sh[(c8 * 8 + j) * 65 + r]);
      *(u16x8*)(dst + (size_t)(td * 64 + r) * 512 + te * 64 + c8 * 8) = o;
    }
  } else if (bi < 256){
    // convert Wv fp32 -> bf16
    size_t e = ((size_t)(bi - 128) * 256 + tid) * 8;
    f32x4 v0 = *(const f32x4*)(Wv + e), v1 = *(const f32x4*)(Wv + e + 4);
    u16x8 o;
    o[0] = f2bf(v0[0]); o[1] = f2bf(v0[1]); o[2] = f2bf(v0[2]); o[3] = f2bf(v0[3]);
    o[4] = f2bf(v1[0]); o[5] = f2bf(v1[1]); o[6] = f2bf(v1[2]); o[7] = f2bf(v1[3]);
    *(u16x8*)(Wv16 + e) = o;
  } else {
    // w1 = SC * Wk^T * bq
    int d = (bi - 256) * 64 + (tid & 63);
    int eq = tid >> 6;
    float s = 0.f;
    #pragma unroll 8
    for (int e = eq * 128; e < eq * 128 + 128; ++e) s += Wk[(size_t)e * 512 + d] * bq[e];
    sh[eq * 64 + (tid & 63)] = s;
    __syncthreads();
    if (eq == 0)
      w1[d] = (sh[tid] + sh[64 + tid] + sh[128 + tid] + sh[192 + tid]) * 0.04419417382415922f;
  }
}

// ---------- features fp32 -> bf16 stacked + column bias v = X*w1 ----------
__global__ void k_conv_feat(const float* __restrict__ f0, const float* __restrict__ f1,
                            const float* __restrict__ f2, const float* __restrict__ w1,
                            unsigned short* __restrict__ Xb, float* __restrict__ vcol){
  size_t i = (size_t)blockIdx.x * blockDim.x + threadIdx.x;
  size_t e = i * 8;
  size_t bt = e >> 19;
  size_t rest = e & ((1u << 19) - 1);
  int b = (int)(bt / 3), t = (int)(bt % 3);
  const float* src = (t == 0 ? f0 : (t == 1 ? f1 : f2)) + ((size_t)b << 19) + rest;
  f32x4 v0 = *(const f32x4*)(src);
  f32x4 v1 = *(const f32x4*)(src + 4);
  u16x8 o;
  o[0] = f2bf(v0[0]); o[1] = f2bf(v0[1]); o[2] = f2bf(v0[2]); o[3] = f2bf(v0[3]);
  o[4] = f2bf(v1[0]); o[5] = f2bf(v1[1]); o[6] = f2bf(v1[2]); o[7] = f2bf(v1[3]);
  *(u16x8*)(Xb + e) = o;
  int l = threadIdx.x & 63;
  f32x4 wa = *(const f32x4*)(w1 + l * 8);
  f32x4 wb = *(const f32x4*)(w1 + l * 8 + 4);
  float p = v0[0]*wa[0] + v0[1]*wa[1] + v0[2]*wa[2] + v0[3]*wa[3]
          + v1[0]*wb[0] + v1[1]*wb[1] + v1[2]*wb[2] + v1[3]*wb[3];
  p += __shfl_xor(p, 1);  p += __shfl_xor(p, 2);  p += __shfl_xor(p, 4);
  p += __shfl_xor(p, 8);  p += __shfl_xor(p, 16); p += __shfl_xor(p, 32);
  if (l == 0) vcol[i >> 6] = p;
}

// ---------- C = (A * B^T + bias) * scale, bf16 out, vectorized LDS epilogue. K=512. ----------
// MODE 0: C[m][n] at m*N+n, bias[n] (nullable)
// MODE 1: C[m][n] at (n>>10)<<19 | m<<10 | (n&1023), bias[m]   (Vt)
template<int MODE>
__global__ __launch_bounds__(256, 2)
void k_gemm_proj(const unsigned short* __restrict__ A, const unsigned short* __restrict__ Bm,
                 const float* __restrict__ bias, unsigned short* __restrict__ C, int N, float scale){
  __shared__ __align__(16) unsigned short Al[2][8192];
  __shared__ __align__(16) unsigned short Bl[2][8192];
  const int tid = threadIdx.x;
  const int l  = tid & 63;
  const int wid = tid >> 6;
  const int lr = l & 15;
  const int lg = l >> 4;
  const int cpx = gridDim.x >> 3;
  const int wg = (blockIdx.x & 7) * cpx + (blockIdx.x >> 3);
  const int nbc = N >> 7;
  int rb, cb;
  if (MODE == 1){ cb = wg >> 2; rb = wg & 3; }
  else          { rb = wg / nbc; cb = wg % nbc; }
  const unsigned short* Ab = A + (size_t)rb * 128 * 512;
  const unsigned short* Bb = Bm + (size_t)cb * 128 * 512;

  const f32x4 zero4 = {0.f, 0.f, 0.f, 0.f};
  f32x4 acc[4][4];
  #pragma unroll
  for (int i = 0; i < 4; ++i)
    #pragma unroll
    for (int j = 0; j < 4; ++j) acc[i][j] = zero4;

  stage_tile(Ab, 512, &Al[0][0], tid);
  stage_tile(Bb, 512, &Bl[0][0], tid);
  __syncthreads();

  const int wr = wid >> 1, wc = wid & 1;

  for (int kb = 0; kb < 8; ++kb){
    const int cur = kb & 1;
    if (kb < 7){
      stage_tile(Ab + (kb + 1) * 64, 512, &Al[cur ^ 1][0], tid);
      stage_tile(Bb + (kb + 1) * 64, 512, &Bl[cur ^ 1][0], tid);
    }
    #pragma unroll
    for (int ks = 0; ks < 2; ++ks){
      bf16x8 af[4], bf[4];
      #pragma unroll
      for (int i = 0; i < 4; ++i) af[i] = frag_at(&Al[cur][0], wr * 64 + i * 16 + lr, ks * 4 + lg);
      #pragma unroll
      for (int j = 0; j < 4; ++j) bf[j] = frag_at(&Bl[cur][0], wc * 64 + j * 16 + lr, ks * 4 + lg);
      #pragma unroll
      for (int i = 0; i < 4; ++i)
        #pragma unroll
        for (int j = 0; j < 4; ++j)
          acc[i][j] = __builtin_amdgcn_mfma_f32_16x16x32_bf16(af[i], bf[j], acc[i][j], 0, 0, 0);
    }
    __syncthreads();
  }

  // ---- epilogue: stage C-tile in LDS, then coalesced u16x8 stores ----
  unsigned short* eL = &Al[0][0];           // [128][128] u16 = 32 KB (dead staging buf)
  #pragma unroll
  for (int j = 0; j < 4; ++j){
    int lcol = wc * 64 + j * 16 + lr;
    float bc = (MODE == 0) ? (bias ? bias[cb * 128 + lcol] : 0.f) : 0.f;
    #pragma unroll
    for (int i = 0; i < 4; ++i){
      int lrow0 = wr * 64 + i * 16 + lg * 4;
      #pragma unroll
      for (int r = 0; r < 4; ++r){
        float v;
        if (MODE == 0) v = (acc[i][j][r] + bc) * scale;
        else           v = acc[i][j][r] + bias[rb * 128 + lrow0 + r];
        eL[(lrow0 + r) * 128 + lcol] = f2bf(v);
      }
    }
  }
  __syncthreads();
  if (MODE == 0){
    #pragma unroll
    for (int q = 0; q < 8; ++q){
      int idx = q * 256 + tid;
      int row = idx >> 4, col = (idx & 15) * 8;
      *(u16x8*)(&C[(size_t)(rb * 128 + row) * N + cb * 128 + col]) =
          *(const u16x8*)(&eL[row * 128 + col]);
    }
  } else {
    size_t base = ((size_t)(cb >> 3) << 19) + (size_t)(cb & 7) * 128;
    #pragma unroll
    for (int q = 0; q < 8; ++q){
      int idx = q * 256 + tid;
      int row = idx >> 4, col = (idx & 15) * 8;
      *(u16x8*)(&C[base + ((size_t)(rb * 128 + row) << 10) + col]) =
          *(const u16x8*)(&eL[row * 128 + col]);
    }
  }
}

// ---------- S = G * X^T, fp16 out (vectorized epilogue). grid = nbt*64, XCD-chunked. ----------
__global__ __launch_bounds__(256, 2)
void k_gemm_qk(const unsigned short* __restrict__ Gb, const unsigned short* __restrict__ Xb,
               unsigned short* __restrict__ S, int bt0){
  __shared__ __align__(16) unsigned short Al[2][8192];
  __shared__ __align__(16) unsigned short Bl[2][8192];
  const int tid = threadIdx.x;
  const int l  = tid & 63;
  const int wid = tid >> 6;
  const int lr = l & 15;
  const int lg = l >> 4;
  const int cpx = gridDim.x >> 3;
  const int wg = (blockIdx.x & 7) * cpx + (blockIdx.x >> 3);
  const int btl = wg >> 6;             // local bt
  const int bt = bt0 + btl;
  const int tile = wg & 63;
  const int rb = tile >> 3, cb = tile & 7;
  const unsigned short* Ab = Gb + ((size_t)bt << 19) + (size_t)rb * 128 * 512;
  const unsigned short* Bb = Xb + ((size_t)bt << 19) + (size_t)cb * 128 * 512;
  unsigned short* Cb = S + ((size_t)btl << 20);

  const f32x4 zero4 = {0.f, 0.f, 0.f, 0.f};
  f32x4 acc[4][4];
  #pragma unroll
  for (int i = 0; i < 4; ++i)
    #pragma unroll
    for (int j = 0; j < 4; ++j) acc[i][j] = zero4;

  stage_tile(Ab, 512, &Al[0][0], tid);
  stage_tile(Bb, 512, &Bl[0][0], tid);
  __syncthreads();

  const int wr = wid >> 1, wc = wid & 1;

  for (int kb = 0; kb < 8; ++kb){
    const int cur = kb & 1;
    if (kb < 7){
      stage_tile(Ab + (kb + 1) * 64, 512, &Al[cur ^ 1][0], tid);
      stage_tile(Bb + (kb + 1) * 64, 512, &Bl[cur ^ 1][0], tid);
    }
    #pragma unroll
    for (int ks = 0; ks < 2; ++ks){
      bf16x8 af[4], bf[4];
      #pragma unroll
      for (int i = 0; i < 4; ++i) af[i] = frag_at(&Al[cur][0], wr * 64 + i * 16 + lr, ks * 4 + lg);
      #pragma unroll
      for (int j = 0; j < 4; ++j) bf[j] = frag_at(&Bl[cur][0], wc * 64 + j * 16 + lr, ks * 4 + lg);
      #pragma unroll
      for (int i = 0; i < 4; ++i)
        #pragma unroll
        for (int j = 0; j < 4; ++j)
          acc[i][j] = __builtin_amdgcn_mfma_f32_16x16x32_bf16(af[i], bf[j], acc[i][j], 0, 0, 0);
    }
    __syncthreads();
  }

  // ---- epilogue: fp16 via LDS, coalesced u16x8 stores ----
  unsigned short* eL = &Al[0][0];
  #pragma unroll
  for (int j = 0; j < 4; ++j){
    int lcol = wc * 64 + j * 16 + lr;
    #pragma unroll
    for (int i = 0; i < 4; ++i){
      int lrow0 = wr * 64 + i * 16 + lg * 4;
      #pragma unroll
      for (int r = 0; r < 4; ++r){
        _Float16 h = (_Float16)acc[i][j][r];
        eL[(lrow0 + r) * 128 + lcol] = __builtin_bit_cast(unsigned short, h);
      }
    }
  }
  __syncthreads();
  #pragma unroll
  for (int q = 0; q < 8; ++q){
    int idx = q * 256 + tid;
    int row = idx >> 4, col = (idx & 15) * 8;
    *(u16x8*)(&Cb[((size_t)(rb * 128 + row) << 10) + cb * 128 + col]) =
        *(const u16x8*)(&eL[row * 128 + col]);
  }
}

// ---------- softmax rows in place: fp16 S (+v col bias) -> bf16 P = w[t]*exp/l ----------
__global__ __launch_bounds__(256)
void k_softmax(unsigned short* __restrict__ S, const float* __restrict__ vcol,
               const float* __restrict__ tfw, int bt0){
  const int wid = threadIdx.x >> 6, l = threadIdx.x & 63;
  const size_t row = (size_t)blockIdx.x * 4 + wid;
  const int bt = bt0 + (int)(row >> 10);
  const int t = bt % 3;
  float t0 = tfw[0], t1 = tfw[1], t2 = tfw[2];
  float tm = fmaxf(t0, fmaxf(t1, t2));
  float e0 = __expf(t0 - tm), e1 = __expf(t1 - tm), e2 = __expf(t2 - tm);
  float w = (t == 0 ? e0 : (t == 1 ? e1 : e2)) / (e0 + e1 + e2);

  const float* vr = vcol + ((size_t)bt << 10) + l * 16;
  unsigned short* rp = S + (row << 10) + l * 16;
  u16x8 a = *(const u16x8*)rp;
  u16x8 b = *(const u16x8*)(rp + 8);
  f32x4 va0 = *(const f32x4*)(vr), va1 = *(const f32x4*)(vr + 4);
  f32x4 va2 = *(const f32x4*)(vr + 8), va3 = *(const f32x4*)(vr + 12);
  float x[16];
  #pragma unroll
  for (int j = 0; j < 8; ++j){
    x[j]     = (float)__builtin_bit_cast(_Float16, (unsigned short)a[j]);
    x[8 + j] = (float)__builtin_bit_cast(_Float16, (unsigned short)b[j]);
  }
  x[0] += va0[0]; x[1] += va0[1]; x[2]  += va0[2]; x[3]  += va0[3];
  x[4] += va1[0]; x[5] += va1[1]; x[6]  += va1[2]; x[7]  += va1[3];
  x[8] += va2[0]; x[9] += va2[1]; x[10] += va2[2]; x[11] += va2[3];
  x[12]+= va3[0]; x[13]+= va3[1]; x[14] += va3[2]; x[15] += va3[3];
  float m = x[0];
  #pragma unroll
  for (int j = 1; j < 16; ++j) m = fmaxf(m, x[j]);
  m = fmaxf(m, __shfl_xor(m, 1));
  m = fmaxf(m, __shfl_xor(m, 2));
  m = fmaxf(m, __shfl_xor(m, 4));
  m = fmaxf(m, __shfl_xor(m, 8));
  m = fmaxf(m, __shfl_xor(m, 16));
  m = fmaxf(m, __shfl_xor(m, 32));
  float s = 0.f;
  #pragma unroll
  for (int j = 0; j < 16; ++j){ x[j] = __expf(x[j] - m); s += x[j]; }
  s += __shfl_xor(s, 1);
  s += __shfl_xor(s, 2);
  s += __shfl_xor(s, 4);
  s += __shfl_xor(s, 8);
  s += __shfl_xor(s, 16);
  s += __shfl_xor(s, 32);
  float sc = w / s;
  u16x8 oa, ob;
  #pragma unroll
  for (int j = 0; j < 8; ++j){
    oa[j] = f2bf(x[j] * sc);
    ob[j] = f2bf(x[8 + j] * sc);
  }
  *(u16x8*)rp = oa;
  *(u16x8*)(rp + 8) = ob;
}

// ---------- out[b] = sum_t P[b,t] * V[b,t], f32 out. grid = nb*32, XCD-chunked. ----------
__global__ __launch_bounds__(256, 2)
void k_gemm_pv(const unsigned short* __restrict__ P, const unsigned short* __restrict__ Vt,
               float* __restrict__ out, int b0){
  __shared__ __align__(16) unsigned short Al[2][8192];
  __shared__ __align__(16) unsigned short Bl[2][8192];
  const int tid = threadIdx.x;
  const int l  = tid & 63;
  const int wid = tid >> 6;
  const int lr = l & 15;
  const int lg = l >> 4;
  const int cpx = gridDim.x >> 3;
  const int wg = (blockIdx.x & 7) * cpx + (blockIdx.x >> 3);
  const int bl = wg >> 5;              // local b
  const int b = b0 + bl;
  const int tile = wg & 31;
  const int rb = tile >> 2, cb = tile & 3;

  const f32x4 zero4 = {0.f, 0.f, 0.f, 0.f};
  f32x4 acc[4][4];
  #pragma unroll
  for (int i = 0; i < 4; ++i)
    #pragma unroll
    for (int j = 0; j < 4; ++j) acc[i][j] = zero4;

  {
    const unsigned short* Ab = P  + ((size_t)(bl * 3) << 20) + (size_t)rb * 128 * 1024;
    const unsigned short* Bb = Vt + ((size_t)(b * 3) << 19) + (size_t)cb * 128 * 1024;
    stage_tile(Ab, 1024, &Al[0][0], tid);
    stage_tile(Bb, 1024, &Bl[0][0], tid);
  }
  __syncthreads();

  const int wr = wid >> 1, wc = wid & 1;

  #pragma unroll 2
  for (int kb = 0; kb < 48; ++kb){
    const int cur = kb & 1;
    if (kb < 47){
      int kn = kb + 1;
      int t = kn >> 4, kk = kn & 15;
      const unsigned short* Ab = P  + ((size_t)(bl * 3 + t) << 20) + (size_t)rb * 128 * 1024 + kk * 64;
      const unsigned short* Bb = Vt + ((size_t)(b * 3 + t) << 19) + (size_t)cb * 128 * 1024 + kk * 64;
      stage_tile(Ab, 1024, &Al[cur ^ 1][0], tid);
      stage_tile(Bb, 1024, &Bl[cur ^ 1][0], tid);
    }
    #pragma unroll
    for (int ks = 0; ks < 2; ++ks){
      bf16x8 af[4], bf[4];
      #pragma unroll
      for (int i = 0; i < 4; ++i) af[i] = frag_at(&Al[cur][0], wr * 64 + i * 16 + lr, ks * 4 + lg);
      #pragma unroll
      for (int j = 0; j < 4; ++j) bf[j] = frag_at(&Bl[cur][0], wc * 64 + j * 16 + lr, ks * 4 + lg);
      #pragma unroll
      for (int i = 0; i < 4; ++i)
        #pragma unroll
        for (int j = 0; j < 4; ++j)
          acc[i][j] = __builtin_amdgcn_mfma_f32_16x16x32_bf16(af[i], bf[j], acc[i][j], 0, 0, 0);
    }
    __syncthreads();
  }

  float* ob = out + ((size_t)b << 19);
  #pragma unroll
  for (int j = 0; j < 4; ++j){
    int col = cb * 128 + wc * 64 + j * 16 + lr;
    #pragma unroll
    for (int i = 0; i < 4; ++i){
      int row0 = rb * 128 + wr * 64 + i * 16 + lg * 4;
      #pragma unroll
      for (int r = 0; r < 4; ++r){
        ob[((size_t)(row0 + r) << 9) + col] = acc[i][j][r];
      }
    }
  }
}

extern "C" void kernel_launch(void* const* d_in, const int* in_sizes, int n_in,
                              void* d_out, int out_size, void* d_ws, size_t ws_size,
                              hipStream_t stream){
  (void)in_sizes; (void)n_in; (void)out_size;
  const float* f4h = (const float*)d_in[0];
  const float* f1d = (const float*)d_in[1];
  const float* f1w = (const float*)d_in[2];
  const float* Wq  = (const float*)d_in[3];
  const float* bq  = (const float*)d_in[4];
  const float* Wk  = (const float*)d_in[5];
  const float* bk  = (const float*)d_in[6];
  const float* Wv  = (const float*)d_in[7];
  const float* bv  = (const float*)d_in[8];
  const float* tfw = (const float*)d_in[9];
  (void)bk;  // row-constant in scores: cancels in softmax
  float* out = (float*)d_out;

  const size_t N48 = (size_t)48 * 1024 * 512;     // 25165824 elems
  unsigned short* Gb  = (unsigned short*)d_ws;
  unsigned short* Xb  = Gb + N48;
  unsigned short* Vt  = Xb + N48;
  float*          vcol = (float*)(Vt + N48);      // 49152 f32
  unsigned short* WqT = (unsigned short*)(vcol + 49152);
  unsigned short* WkT = WqT + 262144;
  unsigned short* Wv16= WkT + 262144;
  unsigned short* Mt  = Wv16 + 262144;
  float*          w1  = (float*)(Mt + 262144);    // 512 f32
  unsigned short* Sb  = WqT;                      // S/P overlays weights region

  const float SC = 0.04419417382415922f;          // 1/sqrt(512)
  const size_t base = 3 * N48 * 2 + 49152 * 4;    // bytes before Sb
  const size_t s_full = (size_t)48 * 1024 * 1024 * 2;

  k_prep<<<264, 256, 0, stream>>>(Wq, Wk, Wv, bq, WqT, WkT, Wv16, w1);
  k_conv_feat<<<12288, 256, 0, stream>>>(f4h, f1d, f1w, w1, Xb, vcol);
  k_gemm_proj<0><<<16, 256, 0, stream>>>(WkT, WqT, nullptr, Mt, 512, SC);   // Mt = SC*WkT*WqT^T
  k_gemm_proj<0><<<1536, 256, 0, stream>>>(Xb, Mt, nullptr, Gb, 512, 1.0f); // Gb = Xb * Mt^T
  k_gemm_proj<1><<<1536, 256, 0, stream>>>(Wv16, Xb, bv, Vt, 49152, 1.0f);  // Vt = Wv Xb^T + bv

  if (ws_size >= base + 2048 + s_full){
    k_gemm_qk<<<3072, 256, 0, stream>>>(Gb, Xb, Sb, 0);
    k_softmax<<<12288, 256, 0, stream>>>(Sb, vcol, tfw, 0);
    k_gemm_pv<<<512, 256, 0, stream>>>(Sb, Vt, out, 0);
  } else {
    for (int h = 0; h < 2; ++h){
      int bt0 = h * 24;
      k_gemm_qk<<<1536, 256, 0, stream>>>(Gb, Xb, Sb, bt0);
      k_softmax<<<6144, 256, 0, stream>>>(Sb, vcol, tfw, bt0);
      k_gemm_pv<<<256, 256, 0, stream>>>(Sb, Vt, out, h * 8);
    }
  }
}